// Round 8
// baseline (389.774 us; speedup 1.0000x reference)
//
#include <hip/hip_runtime.h>

#define B_ 4
#define L_ 4096
#define D_ 1152
#define T_ (B_*L_)      // 16384 tokens
#define D3_ 384
#define H_ 16
#define DK3_ 24

typedef __attribute__((ext_vector_type(4))) float f32x4;
typedef __attribute__((ext_vector_type(8))) __bf16 bf16x8;
typedef __attribute__((ext_vector_type(8))) unsigned short u16x8;
typedef __attribute__((ext_vector_type(4))) unsigned short u16x4;

__device__ __forceinline__ unsigned short f2bf(float f) {
  unsigned int u = __float_as_uint(f);
  u += 0x7fffu + ((u >> 16) & 1u);   // round-to-nearest-even
  return (unsigned short)(u >> 16);
}
__device__ __forceinline__ float bf2f(unsigned short h) {
  return __uint_as_float(((unsigned int)h) << 16);
}

// async global->LDS, 16B per lane. LDS dest wave-uniform; lane l writes dest + l*16.
__device__ __forceinline__ void gl_lds16(const unsigned short* g, unsigned short* l) {
  __builtin_amdgcn_global_load_lds(
      (const __attribute__((address_space(1))) unsigned int*)g,
      (__attribute__((address_space(3))) unsigned int*)l,
      16, 0, 0);
}

// ---------------- LayerNorm: fp32 [16384,1152] -> bf16 [16384,1152] ----------------
__global__ __launch_bounds__(256) void ln_kernel(const float* __restrict__ x,
                                                 const float* __restrict__ gamma,
                                                 const float* __restrict__ beta,
                                                 unsigned short* __restrict__ xn) {
  const int row = blockIdx.x;
  const int tid = threadIdx.x;
  const float4* xr = (const float4*)(x + (size_t)row * D_);
  float4 v0 = xr[tid];
  float4 v1 = {0.f, 0.f, 0.f, 0.f};
  const bool has2 = tid < 32;
  if (has2) v1 = xr[256 + tid];
  float s  = v0.x + v0.y + v0.z + v0.w + v1.x + v1.y + v1.z + v1.w;
  float s2 = v0.x*v0.x + v0.y*v0.y + v0.z*v0.z + v0.w*v0.w
           + v1.x*v1.x + v1.y*v1.y + v1.z*v1.z + v1.w*v1.w;
#pragma unroll
  for (int o = 32; o > 0; o >>= 1) { s += __shfl_down(s, o); s2 += __shfl_down(s2, o); }
  __shared__ float red[8];
  int wid = tid >> 6, lane = tid & 63;
  if (lane == 0) { red[wid] = s; red[4 + wid] = s2; }
  __syncthreads();
  float ts  = red[0] + red[1] + red[2] + red[3];
  float ts2 = red[4] + red[5] + red[6] + red[7];
  const float inv = 1.f / (float)D_;
  float mean = ts * inv;
  float var  = ts2 * inv - mean * mean;
  float rstd = rsqrtf(var + 1e-6f);
  const float4* gm = (const float4*)gamma;
  const float4* bt = (const float4*)beta;
  unsigned short* xo = xn + (size_t)row * D_;
  {
    float4 gv = gm[tid], bv = bt[tid];
    u16x4 r;
    r[0] = f2bf((v0.x - mean) * rstd * gv.x + bv.x);
    r[1] = f2bf((v0.y - mean) * rstd * gv.y + bv.y);
    r[2] = f2bf((v0.z - mean) * rstd * gv.z + bv.z);
    r[3] = f2bf((v0.w - mean) * rstd * gv.w + bv.w);
    *(u16x4*)(xo + tid * 4) = r;
  }
  if (has2) {
    float4 gv = gm[256 + tid], bv = bt[256 + tid];
    u16x4 r;
    r[0] = f2bf((v1.x - mean) * rstd * gv.x + bv.x);
    r[1] = f2bf((v1.y - mean) * rstd * gv.y + bv.y);
    r[2] = f2bf((v1.z - mean) * rstd * gv.z + bv.z);
    r[3] = f2bf((v1.w - mean) * rstd * gv.w + bv.w);
    *(u16x4*)(xo + (256 + tid) * 4) = r;
  }
}

// ---------------- Weight converts ----------------
__global__ void cvt_cat_wqkvg(const float* __restrict__ Wq, const float* __restrict__ Wk,
                              const float* __restrict__ Wv, const float* __restrict__ Wg,
                              unsigned short* __restrict__ out) {
  int i = blockIdx.x * 256 + threadIdx.x;
  if (i >= 4 * 147456) return;
  int p = i / 147456;
  int r = i - p * 147456;
  const float* W = (p == 0) ? Wq : (p == 1) ? Wk : (p == 2) ? Wv : Wg;
  out[i] = f2bf(W[r]);
}

__global__ void cvt_bf16(const float* __restrict__ in, unsigned short* __restrict__ out, int n) {
  int i = blockIdx.x * 256 + threadIdx.x;
  if (i < n) out[i] = f2bf(in[i]);
}

// ---------------- Persistent barrier-free per-wave GEMM ----------------
// Each wave: private 64x64 tile stream, private 16KB LDS double-buffer,
// counted vmcnt(8) only -- NO s_barrier anywhere. 128-thread blocks, 32KB LDS
// -> 5 blocks/CU = 10 independent wave pipelines per CU. Tiles chained:
// a tile's last 2 steps prefetch the next tile's first 2 K-chunks.
// Conflict-free swizzle from round 7 (verified: SQ_LDS_BANK_CONFLICT = 0).

#define NWAVES 2560   // 1280 blocks x 2 waves

template<int EPI, int GX, int NK, int NTOT>
__global__ __launch_bounds__(128) void gemm_pw(
    const unsigned short* __restrict__ A, const unsigned short* __restrict__ Bt,
    unsigned short* __restrict__ Cb,
    const float* __restrict__ b0, const float* __restrict__ b1,
    const float* __restrict__ b2, const float* __restrict__ b3,
    float* __restrict__ Cf, const float* __restrict__ bo,
    const float* __restrict__ xres, const float* __restrict__ gs) {
  constexpr int K = NK * 32;
  constexpr int N = GX * 64;
  __shared__ __align__(16) unsigned short lds[2 * 8192];   // 2 waves x 16KB
  const int tid = threadIdx.x, wid = tid >> 6, lane = tid & 63;
  unsigned short* Wb = lds + wid * 8192;   // wave's private 16KB
  char* Wc = (char*)Wb;                    // slot s: A at s*8192B, B at s*8192+4096B
  const int glr = lane >> 2;
  const int glc = ((lane & 3) ^ ((glr >> 1) & 3)) * 8;     // source swizzle
  const int lrow = lane & 15, kq = lane >> 4;
  const int kqs = (kq ^ ((lrow >> 1) & 3)) * 16;           // read swizzle (bytes)
  const int w = blockIdx.x * 2 + wid;

  int aoff[4], boff[4];
#pragma unroll
  for (int m = 0; m < 4; ++m) aoff[m] = (m * 16 + lrow) * 64 + kqs;
#pragma unroll
  for (int n = 0; n < 4; ++n) boff[n] = (n * 16 + lrow) * 64 + kqs + 4096;

#define STAGE(slot, sa, sb, kk)                                               \
  {                                                                           \
    const unsigned short* a_ = (sa) + (size_t)(kk) * 32 + glc;                \
    const unsigned short* b_ = (sb) + (size_t)(kk) * 32 + glc;                \
    unsigned short* da = Wb + (slot) * 4096;                                  \
    unsigned short* db = da + 2048;                                           \
    _Pragma("unroll")                                                         \
    for (int i_ = 0; i_ < 4; ++i_) {                                          \
      gl_lds16(a_ + (size_t)(i_ * 16 + glr) * K, da + i_ * 512);              \
      gl_lds16(b_ + (size_t)(i_ * 16 + glr) * K, db + i_ * 512);              \
    }                                                                         \
  }

#define KSTEP(WAITN, slot, DOSTAGE, sa, sb, kk)                               \
  {                                                                           \
    asm volatile("s_waitcnt vmcnt(" #WAITN ")" ::: "memory");                 \
    __builtin_amdgcn_sched_barrier(0);                                        \
    bf16x8 af[4], bfr[4];                                                     \
    const char* s_ = Wc + (slot) * 8192;                                      \
    _Pragma("unroll")                                                         \
    for (int m = 0; m < 4; ++m) af[m] = *(const bf16x8*)(s_ + aoff[m]);       \
    _Pragma("unroll")                                                         \
    for (int n = 0; n < 4; ++n) bfr[n] = *(const bf16x8*)(s_ + boff[n]);      \
    asm volatile("s_waitcnt lgkmcnt(0)" ::: "memory");                        \
    __builtin_amdgcn_sched_barrier(0);                                        \
    if (DOSTAGE) STAGE(slot, sa, sb, kk);                                     \
    __builtin_amdgcn_sched_barrier(0);                                        \
    __builtin_amdgcn_s_setprio(1);                                            \
    _Pragma("unroll")                                                         \
    for (int m = 0; m < 4; ++m)                                               \
      _Pragma("unroll")                                                       \
      for (int n = 0; n < 4; ++n)                                             \
        acc[m][n] = __builtin_amdgcn_mfma_f32_16x16x32_bf16(af[m], bfr[n],    \
                                                            acc[m][n], 0,0,0);\
    __builtin_amdgcn_s_setprio(0);                                            \
  }

  int T = w;
  const unsigned short* Ab = A + (size_t)(T / GX) * 64 * K;
  const unsigned short* Bb = Bt + (size_t)(T % GX) * 64 * K;

  // prologue: stage tile T0's k=0,1 (16 loads in flight)
  STAGE(0, Ab, Bb, 0);
  STAGE(1, Ab, Bb, 1);

  while (true) {
    const bool last = (T + NWAVES >= NTOT);
    const unsigned short* Abn = Ab;
    const unsigned short* Bbn = Bb;
    if (!last) {
      int Tn = T + NWAVES;
      Abn = A + (size_t)(Tn / GX) * 64 * K;
      Bbn = Bt + (size_t)(Tn % GX) * 64 * K;
    }
    f32x4 acc[4][4];
#pragma unroll
    for (int m = 0; m < 4; ++m)
#pragma unroll
      for (int n = 0; n < 4; ++n) acc[m][n] = (f32x4){0.f, 0.f, 0.f, 0.f};

    if (!last) {
#pragma unroll 1
      for (int k = 0; k < NK; k += 2) {
        int kk2 = k + 2;
        const unsigned short *sa = Ab, *sb = Bb;
        if (kk2 >= NK) { sa = Abn; sb = Bbn; kk2 -= NK; }
        KSTEP(8, 0, true, sa, sb, kk2);
        int kk3 = k + 3;
        const unsigned short *sa2 = Ab, *sb2 = Bb;
        if (kk3 >= NK) { sa2 = Abn; sb2 = Bbn; kk3 -= NK; }
        KSTEP(8, 1, true, sa2, sb2, kk3);
      }
    } else {
#pragma unroll 1
      for (int k = 0; k < NK - 2; k += 2) {
        KSTEP(8, 0, true, Ab, Bb, k + 2);
        KSTEP(8, 1, (k + 3 < NK), Ab, Bb, (k + 3 < NK) ? k + 3 : 0);
      }
      KSTEP(8, 0, false, Ab, Bb, 0);   // k = NK-2 (NK even -> slot 0)
      KSTEP(0, 1, false, Ab, Bb, 0);   // k = NK-1, final drain
    }

    // Epilogue. D layout: col = lane&15, row = (lane>>4)*4 + reg  [m89-verified]
    {
      const int bm = T / GX, bn = T % GX;
      const int rbase = bm * 64 + kq * 4;
      const int cbase = bn * 64 + lrow;
      float gv = (EPI == 1) ? gs[0] : 0.f;
#pragma unroll
      for (int m = 0; m < 4; ++m) {
#pragma unroll
        for (int n = 0; n < 4; ++n) {
          int col = cbase + n * 16;
          float bias;
          if (EPI == 0) {
            int p = (col < 384) ? 0 : (col < 768) ? 1 : (col < 1152) ? 2 : 3;
            const float* bp = (p == 0) ? b0 : (p == 1) ? b1 : (p == 2) ? b2 : b3;
            bias = bp[col - p * 384];
          } else {
            bias = bo[col];
          }
#pragma unroll
          for (int i = 0; i < 4; ++i) {
            int row = rbase + m * 16 + i;
            float val = acc[m][n][i] + bias;
            if (EPI == 0) {
              Cb[(size_t)row * N + col] = f2bf(val);
            } else {
              size_t idx = (size_t)row * N + col;
              Cf[idx] = val + xres[idx] * gv;
            }
          }
        }
      }
    }

    if (last) break;
    T += NWAVES;
    Ab = Abn;
    Bb = Bbn;
  }
#undef KSTEP
#undef STAGE
}

// ---------------- 3x3 attention + gate: QKVG bf16 [49152,1536] -> H bf16 [16384,1152] ----------------
__global__ __launch_bounds__(256) void attn_kernel(const unsigned short* __restrict__ QKVG,
                                                   unsigned short* __restrict__ Hout) {
  int u = blockIdx.x * 256 + threadIdx.x;   // u = t*48 + i*16 + h
  int h = u & 15;
  int ti = u >> 4;                          // = t*3 + i
  int i = ti % 3;
  int t = ti / 3;
  const unsigned short* base = QKVG + (size_t)t * 3 * 1536;
  const int co = h * 24;

  float q[24];
#pragma unroll
  for (int c = 0; c < 3; ++c) {
    u16x8 w = *(const u16x8*)(base + (size_t)i * 1536 + co + c * 8);
#pragma unroll
    for (int e = 0; e < 8; ++e) q[c * 8 + e] = bf2f(w[e]);
  }
  float s[3];
#pragma unroll
  for (int j = 0; j < 3; ++j) {
    float a = 0.f;
#pragma unroll
    for (int c = 0; c < 3; ++c) {
      u16x8 w = *(const u16x8*)(base + (size_t)j * 1536 + 384 + co + c * 8);
#pragma unroll
      for (int e = 0; e < 8; ++e) a += q[c * 8 + e] * bf2f(w[e]);
    }
    s[j] = a * 0.11785113019775793f;  // 1/sqrt(72)
  }
  float mx = fmaxf(s[0], fmaxf(s[1], s[2]));
  float e0 = __expf(s[0] - mx), e1 = __expf(s[1] - mx), e2 = __expf(s[2] - mx);
  float inv = 1.f / (e0 + e1 + e2);
  float p0 = e0 * inv, p1 = e1 * inv, p2 = e2 * inv;

  float o[24];
#pragma unroll
  for (int d = 0; d < 24; ++d) o[d] = 0.f;
  float pj[3] = {p0, p1, p2};
#pragma unroll
  for (int j = 0; j < 3; ++j) {
#pragma unroll
    for (int c = 0; c < 3; ++c) {
      u16x8 w = *(const u16x8*)(base + (size_t)j * 1536 + 768 + co + c * 8);
#pragma unroll
      for (int e = 0; e < 8; ++e) o[c * 8 + e] += pj[j] * bf2f(w[e]);
    }
  }
  unsigned short* op = Hout + (size_t)t * 1152 + (size_t)i * 384 + co;
#pragma unroll
  for (int c = 0; c < 3; ++c) {
    u16x8 w = *(const u16x8*)(base + (size_t)i * 1536 + 1152 + co + c * 8);
    u16x8 r;
#pragma unroll
    for (int e = 0; e < 8; ++e) {
      float gv = bf2f(w[e]);
      float sg = 1.f / (1.f + __expf(-gv));
      r[e] = f2bf(o[c * 8 + e] * sg);
    }
    *(u16x8*)(op + c * 8) = r;
  }
}

extern "C" void kernel_launch(void* const* d_in, const int* in_sizes, int n_in,
                              void* d_out, int out_size, void* d_ws, size_t ws_size,
                              hipStream_t stream) {
  const float* x    = (const float*)d_in[0];
  const float* ln_g = (const float*)d_in[1];
  const float* ln_b = (const float*)d_in[2];
  const float* Wq   = (const float*)d_in[3];
  const float* bq   = (const float*)d_in[4];
  const float* Wk   = (const float*)d_in[5];
  const float* bk   = (const float*)d_in[6];
  const float* Wv   = (const float*)d_in[7];
  const float* bv   = (const float*)d_in[8];
  const float* Wg   = (const float*)d_in[9];
  const float* bg   = (const float*)d_in[10];
  const float* Wo   = (const float*)d_in[11];
  const float* bo   = (const float*)d_in[12];
  const float* g    = (const float*)d_in[13];
  float* out = (float*)d_out;

  char* ws = (char*)d_ws;
  size_t off = 0;
  unsigned short* xn    = (unsigned short*)(ws + off); off += (size_t)T_ * D_ * 2;
  unsigned short* Wqkvg = (unsigned short*)(ws + off); off += (size_t)1536 * 384 * 2;
  unsigned short* Wob   = (unsigned short*)(ws + off); off += (size_t)1152 * 1152 * 2;
  unsigned short* QKVG  = (unsigned short*)(ws + off); off += (size_t)T_ * 3 * 1536 * 2;
  unsigned short* Hf    = (unsigned short*)(ws + off); off += (size_t)T_ * D_ * 2;

  ln_kernel<<<T_, 256, 0, stream>>>(x, ln_g, ln_b, xn);
  cvt_cat_wqkvg<<<(4 * 147456 + 255) / 256, 256, 0, stream>>>(Wq, Wk, Wv, Wg, Wqkvg);
  cvt_bf16<<<(1152 * 1152 + 255) / 256, 256, 0, stream>>>(Wo, Wob, 1152 * 1152);

  // gemm1: M=49152 (768 row-tiles), N=1536 (24 col-tiles) -> 18432 tiles
  gemm_pw<0, 24, 12, 18432><<<1280, 128, 0, stream>>>(
      xn, Wqkvg, QKVG, bq, bk, bv, bg, nullptr, nullptr, nullptr, nullptr);

  attn_kernel<<<(T_ * H_ * 3) / 256, 256, 0, stream>>>(QKVG, Hf);

  // gemm2: M=16384 (256 row-tiles), N=1152 (18 col-tiles) -> 4608 tiles
  gemm_pw<1, 18, 36, 4608><<<1280, 128, 0, stream>>>(
      Hf, Wob, nullptr, nullptr, nullptr, nullptr, nullptr,
      out, bo, x, g);
}

// Round 9
// 265.713 us; speedup vs baseline: 1.4669x; 1.4669x over previous
//
#include <hip/hip_runtime.h>

#define B_ 4
#define L_ 4096
#define D_ 1152
#define T_ (B_*L_)      // 16384 tokens
#define D3_ 384
#define H_ 16
#define DK3_ 24

typedef __attribute__((ext_vector_type(4))) float f32x4;
typedef __attribute__((ext_vector_type(8))) __bf16 bf16x8;
typedef __attribute__((ext_vector_type(8))) unsigned short u16x8;
typedef __attribute__((ext_vector_type(4))) unsigned short u16x4;

__device__ __forceinline__ unsigned short f2bf(float f) {
  unsigned int u = __float_as_uint(f);
  u += 0x7fffu + ((u >> 16) & 1u);   // round-to-nearest-even
  return (unsigned short)(u >> 16);
}
__device__ __forceinline__ float bf2f(unsigned short h) {
  return __uint_as_float(((unsigned int)h) << 16);
}

// async global->LDS, 16B per lane. LDS dest wave-uniform; lane l writes dest + l*16.
__device__ __forceinline__ void gl_lds16(const unsigned short* g, unsigned short* l) {
  __builtin_amdgcn_global_load_lds(
      (const __attribute__((address_space(1))) unsigned int*)g,
      (__attribute__((address_space(3))) unsigned int*)l,
      16, 0, 0);
}

// ---------------- LayerNorm: fp32 [16384,1152] -> bf16 [16384,1152] ----------------
__global__ __launch_bounds__(256) void ln_kernel(const float* __restrict__ x,
                                                 const float* __restrict__ gamma,
                                                 const float* __restrict__ beta,
                                                 unsigned short* __restrict__ xn) {
  const int row = blockIdx.x;
  const int tid = threadIdx.x;
  const float4* xr = (const float4*)(x + (size_t)row * D_);
  float4 v0 = xr[tid];
  float4 v1 = {0.f, 0.f, 0.f, 0.f};
  const bool has2 = tid < 32;
  if (has2) v1 = xr[256 + tid];
  float s  = v0.x + v0.y + v0.z + v0.w + v1.x + v1.y + v1.z + v1.w;
  float s2 = v0.x*v0.x + v0.y*v0.y + v0.z*v0.z + v0.w*v0.w
           + v1.x*v1.x + v1.y*v1.y + v1.z*v1.z + v1.w*v1.w;
#pragma unroll
  for (int o = 32; o > 0; o >>= 1) { s += __shfl_down(s, o); s2 += __shfl_down(s2, o); }
  __shared__ float red[8];
  int wid = tid >> 6, lane = tid & 63;
  if (lane == 0) { red[wid] = s; red[4 + wid] = s2; }
  __syncthreads();
  float ts  = red[0] + red[1] + red[2] + red[3];
  float ts2 = red[4] + red[5] + red[6] + red[7];
  const float inv = 1.f / (float)D_;
  float mean = ts * inv;
  float var  = ts2 * inv - mean * mean;
  float rstd = rsqrtf(var + 1e-6f);
  const float4* gm = (const float4*)gamma;
  const float4* bt = (const float4*)beta;
  unsigned short* xo = xn + (size_t)row * D_;
  {
    float4 gv = gm[tid], bv = bt[tid];
    u16x4 r;
    r[0] = f2bf((v0.x - mean) * rstd * gv.x + bv.x);
    r[1] = f2bf((v0.y - mean) * rstd * gv.y + bv.y);
    r[2] = f2bf((v0.z - mean) * rstd * gv.z + bv.z);
    r[3] = f2bf((v0.w - mean) * rstd * gv.w + bv.w);
    *(u16x4*)(xo + tid * 4) = r;
  }
  if (has2) {
    float4 gv = gm[256 + tid], bv = bt[256 + tid];
    u16x4 r;
    r[0] = f2bf((v1.x - mean) * rstd * gv.x + bv.x);
    r[1] = f2bf((v1.y - mean) * rstd * gv.y + bv.y);
    r[2] = f2bf((v1.z - mean) * rstd * gv.z + bv.z);
    r[3] = f2bf((v1.w - mean) * rstd * gv.w + bv.w);
    *(u16x4*)(xo + (256 + tid) * 4) = r;
  }
}

// ---------------- Weight converts ----------------
__global__ void cvt_cat_wqkvg(const float* __restrict__ Wq, const float* __restrict__ Wk,
                              const float* __restrict__ Wv, const float* __restrict__ Wg,
                              unsigned short* __restrict__ out) {
  int i = blockIdx.x * 256 + threadIdx.x;
  if (i >= 4 * 147456) return;
  int p = i / 147456;
  int r = i - p * 147456;
  const float* W = (p == 0) ? Wq : (p == 1) ? Wk : (p == 2) ? Wv : Wg;
  out[i] = f2bf(W[r]);
}

__global__ void cvt_bf16(const float* __restrict__ in, unsigned short* __restrict__ out, int n) {
  int i = blockIdx.x * 256 + threadIdx.x;
  if (i < n) out[i] = f2bf(in[i]);
}

// ---------------- bf16 GEMM: C = A @ Bt^T, 256x128 tile, wave-tile 128x64 ----------------
// 4 waves (2M x 2N), 8x4 16x16x32 frags/wave (acc=128 VGPR). BK=32.
// LDS ratio cut: 48KB read per block-step for 2.1 MFLOP (0.75x of 64x64 wave-tile).
// Ring-3 dynamic LDS (3 x 24KB = 72KB -> 2 blocks/CU), counted vmcnt(6),
// ONE barrier per K-step (slot t+2 == slot t-1, protected by barrier(t)).
// R7's verified zero-conflict swizzle. Requires nk % 3 == 0 (12, 36).

template<int EPI>
__global__ __launch_bounds__(256, 2) void gemm_bt(
    const unsigned short* __restrict__ A, const unsigned short* __restrict__ Bt,
    int K, int N,
    unsigned short* __restrict__ Cb,
    const float* __restrict__ b0, const float* __restrict__ b1,
    const float* __restrict__ b2, const float* __restrict__ b3,
    float* __restrict__ Cf, const float* __restrict__ bo,
    const float* __restrict__ xres, const float* __restrict__ gs) {
  extern __shared__ __align__(16) unsigned short lds[];   // 3 slots x 12288 ushorts
  const int tid = threadIdx.x;
  const int nwg = gridDim.x * gridDim.y;
  const int flat = blockIdx.y * gridDim.x + blockIdx.x;
  const int swz = (flat & 7) * (nwg >> 3) + (flat >> 3);
  const int bn = swz % gridDim.x, bm = swz / gridDim.x;

  const int wid = tid >> 6, lane = tid & 63;
  const int wm = wid >> 1, wc = wid & 1;        // wave: rows wm*128, cols wc*64
  const int lrow = lane & 15, kq = lane >> 4;
  const int glr = lane >> 2;                              // 0..15 row in 16-row unit
  const int glc = ((lane & 3) ^ ((glr >> 1) & 3)) * 8;    // pre-swizzled source chunk
  const int kqs = (kq ^ ((lrow >> 1) & 3)) * 16;          // swizzled read chunk (bytes)

  const unsigned short* Ab = A + (size_t)bm * 256 * K;
  const unsigned short* Bb = Bt + (size_t)bn * 128 * K;

  f32x4 acc[8][4];
#pragma unroll
  for (int m = 0; m < 8; ++m)
#pragma unroll
    for (int n = 0; n < 4; ++n) acc[m][n] = (f32x4){0.f, 0.f, 0.f, 0.f};

  // per-frag LDS byte offsets
  int aoff[8], boff[4];
#pragma unroll
  for (int m = 0; m < 8; ++m) aoff[m] = (wm * 128 + m * 16 + lrow) * 64 + kqs;
#pragma unroll
  for (int n = 0; n < 4; ++n) boff[n] = 16384 + (wc * 64 + n * 16 + lrow) * 64 + kqs;

  const int nk = K >> 5;

// stage tile kt into slot J: 24 units of 1KB (A units 0..15, B units 16..23),
// wave wid does units wid*6 .. wid*6+5.
#define STAGE(J, kt)                                                          \
  {                                                                           \
    unsigned short* sb_ = lds + (J) * 12288;                                  \
    _Pragma("unroll")                                                         \
    for (int jj = 0; jj < 6; ++jj) {                                          \
      const int u = wid * 6 + jj;                                             \
      const unsigned short* src;                                              \
      if (u < 16) src = Ab + (size_t)(u * 16 + glr) * K + (kt) * 32 + glc;    \
      else        src = Bb + (size_t)((u - 16) * 16 + glr) * K + (kt) * 32 + glc; \
      gl_lds16(src, sb_ + u * 512);                                           \
    }                                                                         \
  }

// one K-step on slot J; waits own vmcnt to W; stages kt+2 into slot (J+2)%3.
#define KSTEP(J, W, kt, DOSTAGE)                                              \
  {                                                                           \
    asm volatile("s_waitcnt vmcnt(" #W ")" ::: "memory");                     \
    __builtin_amdgcn_sched_barrier(0);                                        \
    __builtin_amdgcn_s_barrier();                                             \
    __builtin_amdgcn_sched_barrier(0);                                        \
    const char* sl = (const char*)lds + (J) * 24576;                          \
    bf16x8 bfr[4], af0[4], af1[4];                                            \
    _Pragma("unroll")                                                         \
    for (int n = 0; n < 4; ++n) bfr[n] = *(const bf16x8*)(sl + boff[n]);      \
    _Pragma("unroll")                                                         \
    for (int m = 0; m < 4; ++m) af0[m] = *(const bf16x8*)(sl + aoff[m]);      \
    if (DOSTAGE) STAGE((J + 2) % 3, (kt) + 2);                                \
    __builtin_amdgcn_s_setprio(1);                                            \
    _Pragma("unroll")                                                         \
    for (int m = 0; m < 4; ++m)                                               \
      _Pragma("unroll")                                                       \
      for (int n = 0; n < 4; ++n)                                             \
        acc[m][n] = __builtin_amdgcn_mfma_f32_16x16x32_bf16(af0[m], bfr[n],   \
                                                            acc[m][n], 0,0,0);\
    __builtin_amdgcn_s_setprio(0);                                            \
    _Pragma("unroll")                                                         \
    for (int m = 0; m < 4; ++m) af1[m] = *(const bf16x8*)(sl + aoff[m + 4]);  \
    __builtin_amdgcn_s_setprio(1);                                            \
    _Pragma("unroll")                                                         \
    for (int m = 0; m < 4; ++m)                                               \
      _Pragma("unroll")                                                       \
      for (int n = 0; n < 4; ++n)                                             \
        acc[m + 4][n] = __builtin_amdgcn_mfma_f32_16x16x32_bf16(af1[m], bfr[n], \
                                                            acc[m + 4][n], 0,0,0);\
    __builtin_amdgcn_s_setprio(0);                                            \
  }

  // prologue: stage tiles 0,1 (12 gl_lds per wave in flight)
  STAGE(0, 0);
  STAGE(1, 1);

  // steady state: wait own oldest tile (6 loads of next tile stay in flight)
  int kt0 = 0;
  for (; kt0 < nk - 3; kt0 += 3) {
    KSTEP(0, 6, kt0, true);
    KSTEP(1, 6, kt0 + 1, true);
    KSTEP(2, 6, kt0 + 2, true);
  }
  KSTEP(0, 6, nk - 3, true);    // stages nk-1
  KSTEP(1, 6, nk - 2, false);
  KSTEP(2, 0, nk - 1, false);

#undef KSTEP
#undef STAGE

  // Epilogue. D layout: col = lane&15, row = (lane>>4)*4 + reg  [m89-verified]
  const int rbase = bm * 256 + wm * 128 + kq * 4;
  const int cbase = bn * 128 + wc * 64 + lrow;
  float gv = (EPI == 1) ? gs[0] : 0.f;
#pragma unroll
  for (int m = 0; m < 8; ++m) {
#pragma unroll
    for (int n = 0; n < 4; ++n) {
      int col = cbase + n * 16;
      float bias;
      if (EPI == 0) {
        int p = (col < 384) ? 0 : (col < 768) ? 1 : (col < 1152) ? 2 : 3;
        const float* bp = (p == 0) ? b0 : (p == 1) ? b1 : (p == 2) ? b2 : b3;
        bias = bp[col - p * 384];
      } else {
        bias = bo[col];
      }
#pragma unroll
      for (int i = 0; i < 4; ++i) {
        int row = rbase + m * 16 + i;
        float val = acc[m][n][i] + bias;
        if (EPI == 0) {
          Cb[(size_t)row * N + col] = f2bf(val);
        } else {
          size_t idx = (size_t)row * N + col;
          Cf[idx] = val + xres[idx] * gv;
        }
      }
    }
  }
}

// ---------------- 3x3 attention + gate: QKVG bf16 [49152,1536] -> H bf16 [16384,1152] ----------------
__global__ __launch_bounds__(256) void attn_kernel(const unsigned short* __restrict__ QKVG,
                                                   unsigned short* __restrict__ Hout) {
  int u = blockIdx.x * 256 + threadIdx.x;   // u = t*48 + i*16 + h
  int h = u & 15;
  int ti = u >> 4;                          // = t*3 + i
  int i = ti % 3;
  int t = ti / 3;
  const unsigned short* base = QKVG + (size_t)t * 3 * 1536;
  const int co = h * 24;

  float q[24];
#pragma unroll
  for (int c = 0; c < 3; ++c) {
    u16x8 w = *(const u16x8*)(base + (size_t)i * 1536 + co + c * 8);
#pragma unroll
    for (int e = 0; e < 8; ++e) q[c * 8 + e] = bf2f(w[e]);
  }
  float s[3];
#pragma unroll
  for (int j = 0; j < 3; ++j) {
    float a = 0.f;
#pragma unroll
    for (int c = 0; c < 3; ++c) {
      u16x8 w = *(const u16x8*)(base + (size_t)j * 1536 + 384 + co + c * 8);
#pragma unroll
      for (int e = 0; e < 8; ++e) a += q[c * 8 + e] * bf2f(w[e]);
    }
    s[j] = a * 0.11785113019775793f;  // 1/sqrt(72)
  }
  float mx = fmaxf(s[0], fmaxf(s[1], s[2]));
  float e0 = __expf(s[0] - mx), e1 = __expf(s[1] - mx), e2 = __expf(s[2] - mx);
  float inv = 1.f / (e0 + e1 + e2);
  float p0 = e0 * inv, p1 = e1 * inv, p2 = e2 * inv;

  float o[24];
#pragma unroll
  for (int d = 0; d < 24; ++d) o[d] = 0.f;
  float pj[3] = {p0, p1, p2};
#pragma unroll
  for (int j = 0; j < 3; ++j) {
#pragma unroll
    for (int c = 0; c < 3; ++c) {
      u16x8 w = *(const u16x8*)(base + (size_t)j * 1536 + 768 + co + c * 8);
#pragma unroll
      for (int e = 0; e < 8; ++e) o[c * 8 + e] += pj[j] * bf2f(w[e]);
    }
  }
  unsigned short* op = Hout + (size_t)t * 1152 + (size_t)i * 384 + co;
#pragma unroll
  for (int c = 0; c < 3; ++c) {
    u16x8 w = *(const u16x8*)(base + (size_t)i * 1536 + 1152 + co + c * 8);
    u16x8 r;
#pragma unroll
    for (int e = 0; e < 8; ++e) {
      float gv = bf2f(w[e]);
      float sg = 1.f / (1.f + __expf(-gv));
      r[e] = f2bf(o[c * 8 + e] * sg);
    }
    *(u16x8*)(op + c * 8) = r;
  }
}

extern "C" void kernel_launch(void* const* d_in, const int* in_sizes, int n_in,
                              void* d_out, int out_size, void* d_ws, size_t ws_size,
                              hipStream_t stream) {
  const float* x    = (const float*)d_in[0];
  const float* ln_g = (const float*)d_in[1];
  const float* ln_b = (const float*)d_in[2];
  const float* Wq   = (const float*)d_in[3];
  const float* bq   = (const float*)d_in[4];
  const float* Wk   = (const float*)d_in[5];
  const float* bk   = (const float*)d_in[6];
  const float* Wv   = (const float*)d_in[7];
  const float* bv   = (const float*)d_in[8];
  const float* Wg   = (const float*)d_in[9];
  const float* bg   = (const float*)d_in[10];
  const float* Wo   = (const float*)d_in[11];
  const float* bo   = (const float*)d_in[12];
  const float* g    = (const float*)d_in[13];
  float* out = (float*)d_out;

  char* ws = (char*)d_ws;
  size_t off = 0;
  unsigned short* xn    = (unsigned short*)(ws + off); off += (size_t)T_ * D_ * 2;
  unsigned short* Wqkvg = (unsigned short*)(ws + off); off += (size_t)1536 * 384 * 2;
  unsigned short* Wob   = (unsigned short*)(ws + off); off += (size_t)1152 * 1152 * 2;
  unsigned short* QKVG  = (unsigned short*)(ws + off); off += (size_t)T_ * 3 * 1536 * 2;
  unsigned short* Hf    = (unsigned short*)(ws + off); off += (size_t)T_ * D_ * 2;

  const int LDS_BYTES = 3 * 24576;  // 72 KB
  (void)hipFuncSetAttribute(reinterpret_cast<const void*>(&gemm_bt<0>),
                            hipFuncAttributeMaxDynamicSharedMemorySize, LDS_BYTES);
  (void)hipFuncSetAttribute(reinterpret_cast<const void*>(&gemm_bt<1>),
                            hipFuncAttributeMaxDynamicSharedMemorySize, LDS_BYTES);

  ln_kernel<<<T_, 256, 0, stream>>>(x, ln_g, ln_b, xn);
  cvt_cat_wqkvg<<<(4 * 147456 + 255) / 256, 256, 0, stream>>>(Wq, Wk, Wv, Wg, Wqkvg);
  cvt_bf16<<<(1152 * 1152 + 255) / 256, 256, 0, stream>>>(Wo, Wob, 1152 * 1152);

  dim3 g1(1536 / 128, (T_ * 3) / 256);   // (12, 192) nwg=2304, %8==0
  gemm_bt<0><<<g1, 256, LDS_BYTES, stream>>>(xn, Wqkvg, 384, 1536, QKVG, bq, bk, bv, bg,
                                             nullptr, nullptr, nullptr, nullptr);

  attn_kernel<<<(T_ * H_ * 3) / 256, 256, 0, stream>>>(QKVG, Hf);

  dim3 g2(1152 / 128, T_ / 256);         // (9, 64) nwg=576, %8==0
  gemm_bt<1><<<g2, 256, LDS_BYTES, stream>>>(Hf, Wob, 1152, 1152,
                                             nullptr, nullptr, nullptr, nullptr, nullptr,
                                             out, bo, x, g);
}

// Round 10
// 261.808 us; speedup vs baseline: 1.4888x; 1.0149x over previous
//
#include <hip/hip_runtime.h>

#define B_ 4
#define L_ 4096
#define D_ 1152
#define T_ (B_*L_)      // 16384 tokens
#define D3_ 384
#define H_ 16
#define DK3_ 24

typedef __attribute__((ext_vector_type(4))) float f32x4;
typedef __attribute__((ext_vector_type(8))) __bf16 bf16x8;
typedef __attribute__((ext_vector_type(8))) unsigned short u16x8;
typedef __attribute__((ext_vector_type(4))) unsigned short u16x4;

__device__ __forceinline__ unsigned short f2bf(float f) {
  unsigned int u = __float_as_uint(f);
  u += 0x7fffu + ((u >> 16) & 1u);   // round-to-nearest-even
  return (unsigned short)(u >> 16);
}
__device__ __forceinline__ float bf2f(unsigned short h) {
  return __uint_as_float(((unsigned int)h) << 16);
}

// async global->LDS, 16B per lane. LDS dest wave-uniform; lane l writes dest + l*16.
__device__ __forceinline__ void gl_lds16(const unsigned short* g, unsigned short* l) {
  __builtin_amdgcn_global_load_lds(
      (const __attribute__((address_space(1))) unsigned int*)g,
      (__attribute__((address_space(3))) unsigned int*)l,
      16, 0, 0);
}

template<int W> __device__ __forceinline__ void waitcnt_vm() {
  if constexpr (W == 8)      asm volatile("s_waitcnt vmcnt(8)" ::: "memory");
  else if constexpr (W == 6) asm volatile("s_waitcnt vmcnt(6)" ::: "memory");
  else if constexpr (W == 4) asm volatile("s_waitcnt vmcnt(4)" ::: "memory");
  else if constexpr (W == 3) asm volatile("s_waitcnt vmcnt(3)" ::: "memory");
  else                       asm volatile("s_waitcnt vmcnt(0)" ::: "memory");
}

// ---------------- LayerNorm: fp32 [16384,1152] -> bf16 [16384,1152] ----------------
__global__ __launch_bounds__(256) void ln_kernel(const float* __restrict__ x,
                                                 const float* __restrict__ gamma,
                                                 const float* __restrict__ beta,
                                                 unsigned short* __restrict__ xn) {
  const int row = blockIdx.x;
  const int tid = threadIdx.x;
  const float4* xr = (const float4*)(x + (size_t)row * D_);
  float4 v0 = xr[tid];
  float4 v1 = {0.f, 0.f, 0.f, 0.f};
  const bool has2 = tid < 32;
  if (has2) v1 = xr[256 + tid];
  float s  = v0.x + v0.y + v0.z + v0.w + v1.x + v1.y + v1.z + v1.w;
  float s2 = v0.x*v0.x + v0.y*v0.y + v0.z*v0.z + v0.w*v0.w
           + v1.x*v1.x + v1.y*v1.y + v1.z*v1.z + v1.w*v1.w;
#pragma unroll
  for (int o = 32; o > 0; o >>= 1) { s += __shfl_down(s, o); s2 += __shfl_down(s2, o); }
  __shared__ float red[8];
  int wid = tid >> 6, lane = tid & 63;
  if (lane == 0) { red[wid] = s; red[4 + wid] = s2; }
  __syncthreads();
  float ts  = red[0] + red[1] + red[2] + red[3];
  float ts2 = red[4] + red[5] + red[6] + red[7];
  const float inv = 1.f / (float)D_;
  float mean = ts * inv;
  float var  = ts2 * inv - mean * mean;
  float rstd = rsqrtf(var + 1e-6f);
  const float4* gm = (const float4*)gamma;
  const float4* bt = (const float4*)beta;
  unsigned short* xo = xn + (size_t)row * D_;
  {
    float4 gv = gm[tid], bv = bt[tid];
    u16x4 r;
    r[0] = f2bf((v0.x - mean) * rstd * gv.x + bv.x);
    r[1] = f2bf((v0.y - mean) * rstd * gv.y + bv.y);
    r[2] = f2bf((v0.z - mean) * rstd * gv.z + bv.z);
    r[3] = f2bf((v0.w - mean) * rstd * gv.w + bv.w);
    *(u16x4*)(xo + tid * 4) = r;
  }
  if (has2) {
    float4 gv = gm[256 + tid], bv = bt[256 + tid];
    u16x4 r;
    r[0] = f2bf((v1.x - mean) * rstd * gv.x + bv.x);
    r[1] = f2bf((v1.y - mean) * rstd * gv.y + bv.y);
    r[2] = f2bf((v1.z - mean) * rstd * gv.z + bv.z);
    r[3] = f2bf((v1.w - mean) * rstd * gv.w + bv.w);
    *(u16x4*)(xo + (256 + tid) * 4) = r;
  }
}

// ---------------- Weight converts ----------------
__global__ void cvt_cat_wqkvg(const float* __restrict__ Wq, const float* __restrict__ Wk,
                              const float* __restrict__ Wv, const float* __restrict__ Wg,
                              unsigned short* __restrict__ out) {
  int i = blockIdx.x * 256 + threadIdx.x;
  if (i >= 4 * 147456) return;
  int p = i / 147456;
  int r = i - p * 147456;
  const float* W = (p == 0) ? Wq : (p == 1) ? Wk : (p == 2) ? Wv : Wg;
  out[i] = f2bf(W[r]);
}

__global__ void cvt_bf16(const float* __restrict__ in, unsigned short* __restrict__ out, int n) {
  int i = blockIdx.x * 256 + threadIdx.x;
  if (i < n) out[i] = f2bf(in[i]);
}

// ---------------- bf16 GEMM: C[M,N] = A[M,K] @ Bt[N,K]^T (+epilogue) ----------------
// Tile 128 x NT (NT=128 for gemm1, NT=96 for gemm2 -> grid 1536 = exactly 2
// rounds at 3 blocks/CU, killing gemm2's 25% tail). 4 waves (2x2),
// wave-tile 64 x NT/2 (4 x NT/32 frags). 3-deep LDS ring + counted vmcnt.
// Zero-conflict swizzle (R7-verified). Requires nk % 3 == 0 (12, 36).

template<int NT>
__device__ __forceinline__ void stage_tile(const unsigned short* Ab, const unsigned short* Bb,
                                           int K, int kt, unsigned short* As_slot,
                                           unsigned short* Bs_slot, int wid, int glr, int glc) {
  if constexpr (NT == 128) {
#pragma unroll
    for (int jj = 0; jj < 2; ++jj) {
      const int rb = wid * 32 + jj * 16;
      gl_lds16(Ab + (size_t)(rb + glr) * K + (size_t)kt * 32 + glc, As_slot + rb * 32);
      gl_lds16(Bb + (size_t)(rb + glr) * K + (size_t)kt * 32 + glc, Bs_slot + rb * 32);
    }
  } else {   // NT == 96: waves 0-1 stage A (4 units), waves 2-3 stage B (3 units)
    if (wid < 2) {
#pragma unroll
      for (int jj = 0; jj < 4; ++jj) {
        const int rb = wid * 64 + jj * 16;
        gl_lds16(Ab + (size_t)(rb + glr) * K + (size_t)kt * 32 + glc, As_slot + rb * 32);
      }
    } else {
#pragma unroll
      for (int jj = 0; jj < 3; ++jj) {
        const int rb = (wid - 2) * 48 + jj * 16;
        gl_lds16(Bb + (size_t)(rb + glr) * K + (size_t)kt * 32 + glc, Bs_slot + rb * 32);
      }
    }
  }
}

template<int EPI, int NT>
__global__ __launch_bounds__(256) void gemm_bt(
    const unsigned short* __restrict__ A, const unsigned short* __restrict__ Bt,
    int K, int N,
    unsigned short* __restrict__ Cb,
    const float* __restrict__ b0, const float* __restrict__ b1,
    const float* __restrict__ b2, const float* __restrict__ b3,
    float* __restrict__ Cf, const float* __restrict__ bo,
    const float* __restrict__ xres, const float* __restrict__ gs) {
  constexpr int NN = NT / 32;            // N-frags per wave
  constexpr int WS = (NT == 128) ? 8 : 6;    // steady vmcnt
  constexpr int WT = (NT == 128) ? 4 : 3;    // tail vmcnt
  __shared__ __align__(16) unsigned short As[3][128 * 32];
  __shared__ __align__(16) unsigned short Bs[3][NT * 32];
  const int tid = threadIdx.x;
  const int nwg = gridDim.x * gridDim.y;
  const int flat = blockIdx.y * gridDim.x + blockIdx.x;
  const int swz = (flat & 7) * (nwg >> 3) + (flat >> 3);
  const int bn = swz % gridDim.x, bm = swz / gridDim.x;

  const int wid = tid >> 6, lane = tid & 63;
  const int wr = wid >> 1, wc = wid & 1;
  const int lrow = lane & 15, kq = lane >> 4;
  const int glr = lane >> 2;                              // 0..15 row within 16-row unit
  const int glc = ((lane & 3) ^ ((glr >> 1) & 3)) * 8;    // pre-swizzled source chunk

  const unsigned short* Ab = A + (size_t)bm * 128 * K;
  const unsigned short* Bb = Bt + (size_t)bn * NT * K;

  f32x4 acc[4][NN];
#pragma unroll
  for (int m = 0; m < 4; ++m)
#pragma unroll
    for (int n = 0; n < NN; ++n) acc[m][n] = (f32x4){0.f, 0.f, 0.f, 0.f};

  // swizzled read byte-offsets (row*64 + (kq^((row>>1)&3))*16)
  const int kqs = (kq ^ ((lrow >> 1) & 3)) * 16;
  int aoff[4], boff[NN];
#pragma unroll
  for (int m = 0; m < 4; ++m) aoff[m] = (wr * 64 + m * 16 + lrow) * 64 + kqs;
#pragma unroll
  for (int n = 0; n < NN; ++n) boff[n] = (wc * (NT / 2) + n * 16 + lrow) * 64 + kqs;

  const int nk = K >> 5;

// One K-step on ring slot J, waiting own vmcnt down to W; optionally stage kt+3.
#define KSTEP(J, W, kt, DOSTAGE)                                              \
  {                                                                           \
    waitcnt_vm<(W)>();                                                        \
    __builtin_amdgcn_sched_barrier(0);                                        \
    __builtin_amdgcn_s_barrier();                                             \
    __builtin_amdgcn_sched_barrier(0);                                        \
    bf16x8 af[4], bfr[NN];                                                    \
    _Pragma("unroll")                                                         \
    for (int m = 0; m < 4; ++m)                                               \
      af[m] = *(const bf16x8*)((const char*)As[J] + aoff[m]);                 \
    _Pragma("unroll")                                                         \
    for (int n = 0; n < NN; ++n)                                              \
      bfr[n] = *(const bf16x8*)((const char*)Bs[J] + boff[n]);                \
    asm volatile("s_waitcnt lgkmcnt(0)" ::: "memory");                        \
    __builtin_amdgcn_sched_barrier(0);                                        \
    __builtin_amdgcn_s_barrier();                                             \
    __builtin_amdgcn_sched_barrier(0);                                        \
    if (DOSTAGE) stage_tile<NT>(Ab, Bb, K, (kt) + 3, As[J], Bs[J], wid, glr, glc); \
    __builtin_amdgcn_sched_barrier(0);                                        \
    _Pragma("unroll")                                                         \
    for (int m = 0; m < 4; ++m)                                               \
      _Pragma("unroll")                                                       \
      for (int n = 0; n < NN; ++n)                                            \
        acc[m][n] = __builtin_amdgcn_mfma_f32_16x16x32_bf16(af[m], bfr[n],    \
                                                            acc[m][n], 0,0,0);\
  }

  // prologue: stage tiles 0,1,2
  stage_tile<NT>(Ab, Bb, K, 0, As[0], Bs[0], wid, glr, glc);
  stage_tile<NT>(Ab, Bb, K, 1, As[1], Bs[1], wid, glr, glc);
  stage_tile<NT>(Ab, Bb, K, 2, As[2], Bs[2], wid, glr, glc);

  // steady state: 2 tiles stay in flight past each wait; loop stages through nk-1
  int kt0 = 0;
  for (; kt0 < nk - 3; kt0 += 3) {
    KSTEP(0, WS, kt0, true);
    KSTEP(1, WS, kt0 + 1, true);
    KSTEP(2, WS, kt0 + 2, true);
  }
  // tail triple: all tiles already staged; drain WS -> WT -> 0
  KSTEP(0, WS, nk - 3, false);
  KSTEP(1, WT, nk - 2, false);
  KSTEP(2, 0, nk - 1, false);

#undef KSTEP

  // Epilogue. D layout: col = lane&15, row = (lane>>4)*4 + reg  [m89-verified]
  const int rbase = bm * 128 + wr * 64 + kq * 4;
  const int cbase = bn * NT + wc * (NT / 2) + lrow;
  float gv = (EPI == 1) ? gs[0] : 0.f;
#pragma unroll
  for (int m = 0; m < 4; ++m) {
#pragma unroll
    for (int n = 0; n < NN; ++n) {
      int col = cbase + n * 16;
      float bias;
      if (EPI == 0) {
        int p = (col < 384) ? 0 : (col < 768) ? 1 : (col < 1152) ? 2 : 3;
        const float* bp = (p == 0) ? b0 : (p == 1) ? b1 : (p == 2) ? b2 : b3;
        bias = bp[col - p * 384];
      } else {
        bias = bo[col];
      }
#pragma unroll
      for (int i = 0; i < 4; ++i) {
        int row = rbase + m * 16 + i;
        float val = acc[m][n][i] + bias;
        if (EPI == 0) {
          Cb[(size_t)row * N + col] = f2bf(val);
        } else {
          size_t idx = (size_t)row * N + col;
          Cf[idx] = val + xres[idx] * gv;
        }
      }
    }
  }
}

// ---------------- 3x3 attention + gate: QKVG bf16 [49152,1536] -> H bf16 [16384,1152] ----------------
__global__ __launch_bounds__(256) void attn_kernel(const unsigned short* __restrict__ QKVG,
                                                   unsigned short* __restrict__ Hout) {
  int u = blockIdx.x * 256 + threadIdx.x;   // u = t*48 + i*16 + h
  int h = u & 15;
  int ti = u >> 4;                          // = t*3 + i
  int i = ti % 3;
  int t = ti / 3;
  const unsigned short* base = QKVG + (size_t)t * 3 * 1536;
  const int co = h * 24;

  float q[24];
#pragma unroll
  for (int c = 0; c < 3; ++c) {
    u16x8 w = *(const u16x8*)(base + (size_t)i * 1536 + co + c * 8);
#pragma unroll
    for (int e = 0; e < 8; ++e) q[c * 8 + e] = bf2f(w[e]);
  }
  float s[3];
#pragma unroll
  for (int j = 0; j < 3; ++j) {
    float a = 0.f;
#pragma unroll
    for (int c = 0; c < 3; ++c) {
      u16x8 w = *(const u16x8*)(base + (size_t)j * 1536 + 384 + co + c * 8);
#pragma unroll
      for (int e = 0; e < 8; ++e) a += q[c * 8 + e] * bf2f(w[e]);
    }
    s[j] = a * 0.11785113019775793f;  // 1/sqrt(72)
  }
  float mx = fmaxf(s[0], fmaxf(s[1], s[2]));
  float e0 = __expf(s[0] - mx), e1 = __expf(s[1] - mx), e2 = __expf(s[2] - mx);
  float inv = 1.f / (e0 + e1 + e2);
  float p0 = e0 * inv, p1 = e1 * inv, p2 = e2 * inv;

  float o[24];
#pragma unroll
  for (int d = 0; d < 24; ++d) o[d] = 0.f;
  float pj[3] = {p0, p1, p2};
#pragma unroll
  for (int j = 0; j < 3; ++j) {
#pragma unroll
    for (int c = 0; c < 3; ++c) {
      u16x8 w = *(const u16x8*)(base + (size_t)j * 1536 + 768 + co + c * 8);
#pragma unroll
      for (int e = 0; e < 8; ++e) o[c * 8 + e] += pj[j] * bf2f(w[e]);
    }
  }
  unsigned short* op = Hout + (size_t)t * 1152 + (size_t)i * 384 + co;
#pragma unroll
  for (int c = 0; c < 3; ++c) {
    u16x8 w = *(const u16x8*)(base + (size_t)i * 1536 + 1152 + co + c * 8);
    u16x8 r;
#pragma unroll
    for (int e = 0; e < 8; ++e) {
      float gv = bf2f(w[e]);
      float sg = 1.f / (1.f + __expf(-gv));
      r[e] = f2bf(o[c * 8 + e] * sg);
    }
    *(u16x8*)(op + c * 8) = r;
  }
}

extern "C" void kernel_launch(void* const* d_in, const int* in_sizes, int n_in,
                              void* d_out, int out_size, void* d_ws, size_t ws_size,
                              hipStream_t stream) {
  const float* x    = (const float*)d_in[0];
  const float* ln_g = (const float*)d_in[1];
  const float* ln_b = (const float*)d_in[2];
  const float* Wq   = (const float*)d_in[3];
  const float* bq   = (const float*)d_in[4];
  const float* Wk   = (const float*)d_in[5];
  const float* bk   = (const float*)d_in[6];
  const float* Wv   = (const float*)d_in[7];
  const float* bv   = (const float*)d_in[8];
  const float* Wg   = (const float*)d_in[9];
  const float* bg   = (const float*)d_in[10];
  const float* Wo   = (const float*)d_in[11];
  const float* bo   = (const float*)d_in[12];
  const float* g    = (const float*)d_in[13];
  float* out = (float*)d_out;

  char* ws = (char*)d_ws;
  size_t off = 0;
  unsigned short* xn    = (unsigned short*)(ws + off); off += (size_t)T_ * D_ * 2;
  unsigned short* Wqkvg = (unsigned short*)(ws + off); off += (size_t)1536 * 384 * 2;
  unsigned short* Wob   = (unsigned short*)(ws + off); off += (size_t)1152 * 1152 * 2;
  unsigned short* QKVG  = (unsigned short*)(ws + off); off += (size_t)T_ * 3 * 1536 * 2;
  unsigned short* Hf    = (unsigned short*)(ws + off); off += (size_t)T_ * D_ * 2;

  ln_kernel<<<T_, 256, 0, stream>>>(x, ln_g, ln_b, xn);
  cvt_cat_wqkvg<<<(4 * 147456 + 255) / 256, 256, 0, stream>>>(Wq, Wk, Wv, Wg, Wqkvg);
  cvt_bf16<<<(1152 * 1152 + 255) / 256, 256, 0, stream>>>(Wo, Wob, 1152 * 1152);

  dim3 g1(1536 / 128, (T_ * 3) / 128);   // (12, 384) nwg=4608 = 6.0 rounds @3/CU
  gemm_bt<0, 128><<<g1, 256, 0, stream>>>(xn, Wqkvg, 384, 1536, QKVG, bq, bk, bv, bg,
                                          nullptr, nullptr, nullptr, nullptr);

  attn_kernel<<<(T_ * H_ * 3) / 256, 256, 0, stream>>>(QKVG, Hf);

  dim3 g2(1152 / 96, T_ / 128);          // (12, 128) nwg=1536 = 2.0 rounds @3/CU
  gemm_bt<1, 96><<<g2, 256, 0, stream>>>(Hf, Wob, 1152, 1152,
                                         nullptr, nullptr, nullptr, nullptr, nullptr,
                                         out, bo, x, g);
}

// Round 11
// 248.655 us; speedup vs baseline: 1.5675x; 1.0529x over previous
//
#include <hip/hip_runtime.h>

#define B_ 4
#define L_ 4096
#define D_ 1152
#define T_ (B_*L_)      // 16384 tokens
#define D3_ 384
#define H_ 16
#define DK3_ 24

typedef __attribute__((ext_vector_type(4))) float f32x4;
typedef __attribute__((ext_vector_type(8))) __bf16 bf16x8;
typedef __attribute__((ext_vector_type(8))) unsigned short u16x8;
typedef __attribute__((ext_vector_type(4))) unsigned short u16x4;

__device__ __forceinline__ unsigned short f2bf(float f) {
  unsigned int u = __float_as_uint(f);
  u += 0x7fffu + ((u >> 16) & 1u);   // round-to-nearest-even
  return (unsigned short)(u >> 16);
}
__device__ __forceinline__ float bf2f(unsigned short h) {
  return __uint_as_float(((unsigned int)h) << 16);
}

// async global->LDS, 16B per lane. LDS dest wave-uniform; lane l writes dest + l*16.
__device__ __forceinline__ void gl_lds16(const unsigned short* g, unsigned short* l) {
  __builtin_amdgcn_global_load_lds(
      (const __attribute__((address_space(1))) unsigned int*)g,
      (__attribute__((address_space(3))) unsigned int*)l,
      16, 0, 0);
}

template<int W> __device__ __forceinline__ void waitcnt_vm() {
  if constexpr (W == 8)      asm volatile("s_waitcnt vmcnt(8)" ::: "memory");
  else if constexpr (W == 6) asm volatile("s_waitcnt vmcnt(6)" ::: "memory");
  else if constexpr (W == 4) asm volatile("s_waitcnt vmcnt(4)" ::: "memory");
  else if constexpr (W == 3) asm volatile("s_waitcnt vmcnt(3)" ::: "memory");
  else if constexpr (W == 2) asm volatile("s_waitcnt vmcnt(2)" ::: "memory");
  else                       asm volatile("s_waitcnt vmcnt(0)" ::: "memory");
}

// ---------------- LayerNorm: fp32 [16384,1152] -> bf16 [16384,1152] ----------------
__global__ __launch_bounds__(256) void ln_kernel(const float* __restrict__ x,
                                                 const float* __restrict__ gamma,
                                                 const float* __restrict__ beta,
                                                 unsigned short* __restrict__ xn) {
  const int row = blockIdx.x;
  const int tid = threadIdx.x;
  const float4* xr = (const float4*)(x + (size_t)row * D_);
  float4 v0 = xr[tid];
  float4 v1 = {0.f, 0.f, 0.f, 0.f};
  const bool has2 = tid < 32;
  if (has2) v1 = xr[256 + tid];
  float s  = v0.x + v0.y + v0.z + v0.w + v1.x + v1.y + v1.z + v1.w;
  float s2 = v0.x*v0.x + v0.y*v0.y + v0.z*v0.z + v0.w*v0.w
           + v1.x*v1.x + v1.y*v1.y + v1.z*v1.z + v1.w*v1.w;
#pragma unroll
  for (int o = 32; o > 0; o >>= 1) { s += __shfl_down(s, o); s2 += __shfl_down(s2, o); }
  __shared__ float red[8];
  int wid = tid >> 6, lane = tid & 63;
  if (lane == 0) { red[wid] = s; red[4 + wid] = s2; }
  __syncthreads();
  float ts  = red[0] + red[1] + red[2] + red[3];
  float ts2 = red[4] + red[5] + red[6] + red[7];
  const float inv = 1.f / (float)D_;
  float mean = ts * inv;
  float var  = ts2 * inv - mean * mean;
  float rstd = rsqrtf(var + 1e-6f);
  const float4* gm = (const float4*)gamma;
  const float4* bt = (const float4*)beta;
  unsigned short* xo = xn + (size_t)row * D_;
  {
    float4 gv = gm[tid], bv = bt[tid];
    u16x4 r;
    r[0] = f2bf((v0.x - mean) * rstd * gv.x + bv.x);
    r[1] = f2bf((v0.y - mean) * rstd * gv.y + bv.y);
    r[2] = f2bf((v0.z - mean) * rstd * gv.z + bv.z);
    r[3] = f2bf((v0.w - mean) * rstd * gv.w + bv.w);
    *(u16x4*)(xo + tid * 4) = r;
  }
  if (has2) {
    float4 gv = gm[256 + tid], bv = bt[256 + tid];
    u16x4 r;
    r[0] = f2bf((v1.x - mean) * rstd * gv.x + bv.x);
    r[1] = f2bf((v1.y - mean) * rstd * gv.y + bv.y);
    r[2] = f2bf((v1.z - mean) * rstd * gv.z + bv.z);
    r[3] = f2bf((v1.w - mean) * rstd * gv.w + bv.w);
    *(u16x4*)(xo + (256 + tid) * 4) = r;
  }
}

// ---------------- Weight converts ----------------
__global__ void cvt_cat_wqkvg(const float* __restrict__ Wq, const float* __restrict__ Wk,
                              const float* __restrict__ Wv, const float* __restrict__ Wg,
                              unsigned short* __restrict__ out) {
  int i = blockIdx.x * 256 + threadIdx.x;
  if (i >= 4 * 147456) return;
  int p = i / 147456;
  int r = i - p * 147456;
  const float* W = (p == 0) ? Wq : (p == 1) ? Wk : (p == 2) ? Wv : Wg;
  out[i] = f2bf(W[r]);
}

__global__ void cvt_bf16(const float* __restrict__ in, unsigned short* __restrict__ out, int n) {
  int i = blockIdx.x * 256 + threadIdx.x;
  if (i < n) out[i] = f2bf(in[i]);
}

// ---------------- gemm1 (high-occupancy): C[M,1536] = A[M,384] @ Bt[1536,384]^T ----------------
// BM=128, BN=128, BK=32. 512 threads = 8 waves (2M x 4N), wave-tile 64x32
// (4x2 frags, acc=32 VGPR). Ring-3 LDS = 48KB -> 3 blocks/CU = 24 waves/CU
// (6 waves/SIMD; launch_bounds caps VGPR at 85). Counted vmcnt(4) steady
// (2 tiles x 2 loads in flight), R10's proven 2-barrier KSTEP, zero-conflict
// swizzle (R7-verified formulas). nk = 12.

__global__ __launch_bounds__(512, 6) void gemm1_hi(
    const unsigned short* __restrict__ A, const unsigned short* __restrict__ Bt,
    unsigned short* __restrict__ Cb,
    const float* __restrict__ b0, const float* __restrict__ b1,
    const float* __restrict__ b2, const float* __restrict__ b3) {
  const int K = 384, N = 1536;
  __shared__ __align__(16) unsigned short As[3][128 * 32];
  __shared__ __align__(16) unsigned short Bs[3][128 * 32];
  const int tid = threadIdx.x;
  const int nwg = gridDim.x * gridDim.y;
  const int flat = blockIdx.y * gridDim.x + blockIdx.x;
  const int swz = (flat & 7) * (nwg >> 3) + (flat >> 3);
  const int bn = swz % gridDim.x, bm = swz / gridDim.x;

  const int wid = tid >> 6, lane = tid & 63;
  const int wm = wid >> 2, wn = wid & 3;     // wave tile: rows wm*64, cols wn*32
  const int lrow = lane & 15, kq = lane >> 4;
  const int glr = lane >> 2;                              // 0..15 row within 16-row unit
  const int glc = ((lane & 3) ^ ((glr >> 1) & 3)) * 8;    // pre-swizzled source chunk
  const int kqs = (kq ^ ((lrow >> 1) & 3)) * 16;          // swizzled read chunk (bytes)

  const unsigned short* Ab = A + (size_t)bm * 128 * K;
  const unsigned short* Bb = Bt + (size_t)bn * 128 * K;

  f32x4 acc[4][2];
#pragma unroll
  for (int m = 0; m < 4; ++m)
#pragma unroll
    for (int n = 0; n < 2; ++n) acc[m][n] = (f32x4){0.f, 0.f, 0.f, 0.f};

  int aoff[4], boff[2];
#pragma unroll
  for (int m = 0; m < 4; ++m) aoff[m] = (wm * 64 + m * 16 + lrow) * 64 + kqs;
#pragma unroll
  for (int n = 0; n < 2; ++n) boff[n] = (wn * 32 + n * 16 + lrow) * 64 + kqs;

  const int nk = 12;

// stage tile kt into slot J: each wave stages its 16-row A unit + 16-row B unit.
#define STAGE(J, kt)                                                          \
  {                                                                           \
    gl_lds16(Ab + (size_t)(wid * 16 + glr) * K + (kt) * 32 + glc,             \
             &As[J][wid * 512]);                                              \
    gl_lds16(Bb + (size_t)(wid * 16 + glr) * K + (kt) * 32 + glc,             \
             &Bs[J][wid * 512]);                                              \
  }

#define KSTEP(J, W, kt, DOSTAGE)                                              \
  {                                                                           \
    waitcnt_vm<(W)>();                                                        \
    __builtin_amdgcn_sched_barrier(0);                                        \
    __builtin_amdgcn_s_barrier();                                             \
    __builtin_amdgcn_sched_barrier(0);                                        \
    bf16x8 af[4], bfr[2];                                                     \
    _Pragma("unroll")                                                         \
    for (int m = 0; m < 4; ++m)                                               \
      af[m] = *(const bf16x8*)((const char*)As[J] + aoff[m]);                 \
    _Pragma("unroll")                                                         \
    for (int n = 0; n < 2; ++n)                                               \
      bfr[n] = *(const bf16x8*)((const char*)Bs[J] + boff[n]);                \
    asm volatile("s_waitcnt lgkmcnt(0)" ::: "memory");                        \
    __builtin_amdgcn_sched_barrier(0);                                        \
    __builtin_amdgcn_s_barrier();                                             \
    __builtin_amdgcn_sched_barrier(0);                                        \
    if (DOSTAGE) STAGE(J, (kt) + 3);                                          \
    __builtin_amdgcn_sched_barrier(0);                                        \
    _Pragma("unroll")                                                         \
    for (int m = 0; m < 4; ++m)                                               \
      _Pragma("unroll")                                                       \
      for (int n = 0; n < 2; ++n)                                             \
        acc[m][n] = __builtin_amdgcn_mfma_f32_16x16x32_bf16(af[m], bfr[n],    \
                                                            acc[m][n], 0,0,0);\
  }

  // prologue: stage tiles 0,1,2 (6 loads/thread in flight)
  STAGE(0, 0);
  STAGE(1, 1);
  STAGE(2, 2);

  // steady: 2 tiles (4 loads) stay in flight past each wait
  int kt0 = 0;
  for (; kt0 < nk - 3; kt0 += 3) {
    KSTEP(0, 4, kt0, true);
    KSTEP(1, 4, kt0 + 1, true);
    KSTEP(2, 4, kt0 + 2, true);
  }
  KSTEP(0, 4, nk - 3, false);
  KSTEP(1, 2, nk - 2, false);
  KSTEP(2, 0, nk - 1, false);

#undef KSTEP
#undef STAGE

  // Epilogue. D layout: col = lane&15, row = (lane>>4)*4 + reg  [m89-verified]
  const int rbase = bm * 128 + wm * 64 + kq * 4;
  const int cbase = bn * 128 + wn * 32 + lrow;
#pragma unroll
  for (int m = 0; m < 4; ++m) {
#pragma unroll
    for (int n = 0; n < 2; ++n) {
      int col = cbase + n * 16;
      int p = (col < 384) ? 0 : (col < 768) ? 1 : (col < 1152) ? 2 : 3;
      const float* bp = (p == 0) ? b0 : (p == 1) ? b1 : (p == 2) ? b2 : b3;
      float bias = bp[col - p * 384];
#pragma unroll
      for (int i = 0; i < 4; ++i) {
        int row = rbase + m * 16 + i;
        Cb[(size_t)row * N + col] = f2bf(acc[m][n][i] + bias);
      }
    }
  }
}

// ---------------- gemm2 (R10 structure, NT=96): out = Hf @ Wo^T + bo + x*g ----------------
__device__ __forceinline__ void stage_tile96(const unsigned short* Ab, const unsigned short* Bb,
                                             int K, int kt, unsigned short* As_slot,
                                             unsigned short* Bs_slot, int wid, int glr, int glc) {
  if (wid < 2) {
#pragma unroll
    for (int jj = 0; jj < 4; ++jj) {
      const int rb = wid * 64 + jj * 16;
      gl_lds16(Ab + (size_t)(rb + glr) * K + (size_t)kt * 32 + glc, As_slot + rb * 32);
    }
  } else {
#pragma unroll
    for (int jj = 0; jj < 3; ++jj) {
      const int rb = (wid - 2) * 48 + jj * 16;
      gl_lds16(Bb + (size_t)(rb + glr) * K + (size_t)kt * 32 + glc, Bs_slot + rb * 32);
    }
  }
}

__global__ __launch_bounds__(256) void gemm2_96(
    const unsigned short* __restrict__ A, const unsigned short* __restrict__ Bt,
    float* __restrict__ Cf, const float* __restrict__ bo,
    const float* __restrict__ xres, const float* __restrict__ gs) {
  const int K = 1152, N = 1152, NT = 96;
  __shared__ __align__(16) unsigned short As[3][128 * 32];
  __shared__ __align__(16) unsigned short Bs[3][NT * 32];
  const int tid = threadIdx.x;
  const int nwg = gridDim.x * gridDim.y;
  const int flat = blockIdx.y * gridDim.x + blockIdx.x;
  const int swz = (flat & 7) * (nwg >> 3) + (flat >> 3);
  const int bn = swz % gridDim.x, bm = swz / gridDim.x;

  const int wid = tid >> 6, lane = tid & 63;
  const int wr = wid >> 1, wc = wid & 1;
  const int lrow = lane & 15, kq = lane >> 4;
  const int glr = lane >> 2;
  const int glc = ((lane & 3) ^ ((glr >> 1) & 3)) * 8;

  const unsigned short* Ab = A + (size_t)bm * 128 * K;
  const unsigned short* Bb = Bt + (size_t)bn * NT * K;

  f32x4 acc[4][3];
#pragma unroll
  for (int m = 0; m < 4; ++m)
#pragma unroll
    for (int n = 0; n < 3; ++n) acc[m][n] = (f32x4){0.f, 0.f, 0.f, 0.f};

  const int kqs = (kq ^ ((lrow >> 1) & 3)) * 16;
  int aoff[4], boff[3];
#pragma unroll
  for (int m = 0; m < 4; ++m) aoff[m] = (wr * 64 + m * 16 + lrow) * 64 + kqs;
#pragma unroll
  for (int n = 0; n < 3; ++n) boff[n] = (wc * 48 + n * 16 + lrow) * 64 + kqs;

  const int nk = K >> 5;   // 36

#define KSTEP2(J, W, kt, DOSTAGE)                                             \
  {                                                                           \
    waitcnt_vm<(W)>();                                                        \
    __builtin_amdgcn_sched_barrier(0);                                        \
    __builtin_amdgcn_s_barrier();                                             \
    __builtin_amdgcn_sched_barrier(0);                                        \
    bf16x8 af[4], bfr[3];                                                     \
    _Pragma("unroll")                                                         \
    for (int m = 0; m < 4; ++m)                                               \
      af[m] = *(const bf16x8*)((const char*)As[J] + aoff[m]);                 \
    _Pragma("unroll")                                                         \
    for (int n = 0; n < 3; ++n)                                               \
      bfr[n] = *(const bf16x8*)((const char*)Bs[J] + boff[n]);                \
    asm volatile("s_waitcnt lgkmcnt(0)" ::: "memory");                        \
    __builtin_amdgcn_sched_barrier(0);                                        \
    __builtin_amdgcn_s_barrier();                                             \
    __builtin_amdgcn_sched_barrier(0);                                        \
    if (DOSTAGE) stage_tile96(Ab, Bb, K, (kt) + 3, As[J], Bs[J], wid, glr, glc); \
    __builtin_amdgcn_sched_barrier(0);                                        \
    _Pragma("unroll")                                                         \
    for (int m = 0; m < 4; ++m)                                               \
      _Pragma("unroll")                                                       \
      for (int n = 0; n < 3; ++n)                                             \
        acc[m][n] = __builtin_amdgcn_mfma_f32_16x16x32_bf16(af[m], bfr[n],    \
                                                            acc[m][n], 0,0,0);\
  }

  stage_tile96(Ab, Bb, K, 0, As[0], Bs[0], wid, glr, glc);
  stage_tile96(Ab, Bb, K, 1, As[1], Bs[1], wid, glr, glc);
  stage_tile96(Ab, Bb, K, 2, As[2], Bs[2], wid, glr, glc);

  int kt0 = 0;
  for (; kt0 < nk - 3; kt0 += 3) {
    KSTEP2(0, 6, kt0, true);
    KSTEP2(1, 6, kt0 + 1, true);
    KSTEP2(2, 6, kt0 + 2, true);
  }
  KSTEP2(0, 6, nk - 3, false);
  KSTEP2(1, 3, nk - 2, false);
  KSTEP2(2, 0, nk - 1, false);

#undef KSTEP2

  const int rbase = bm * 128 + wr * 64 + kq * 4;
  const int cbase = bn * NT + wc * 48 + lrow;
  float gv = gs[0];
#pragma unroll
  for (int m = 0; m < 4; ++m) {
#pragma unroll
    for (int n = 0; n < 3; ++n) {
      int col = cbase + n * 16;
      float bias = bo[col];
#pragma unroll
      for (int i = 0; i < 4; ++i) {
        int row = rbase + m * 16 + i;
        size_t idx = (size_t)row * N + col;
        Cf[idx] = acc[m][n][i] + bias + xres[idx] * gv;
      }
    }
  }
}

// ---------------- 3x3 attention + gate: QKVG bf16 [49152,1536] -> H bf16 [16384,1152] ----------------
__global__ __launch_bounds__(256) void attn_kernel(const unsigned short* __restrict__ QKVG,
                                                   unsigned short* __restrict__ Hout) {
  int u = blockIdx.x * 256 + threadIdx.x;   // u = t*48 + i*16 + h
  int h = u & 15;
  int ti = u >> 4;                          // = t*3 + i
  int i = ti % 3;
  int t = ti / 3;
  const unsigned short* base = QKVG + (size_t)t * 3 * 1536;
  const int co = h * 24;

  float q[24];
#pragma unroll
  for (int c = 0; c < 3; ++c) {
    u16x8 w = *(const u16x8*)(base + (size_t)i * 1536 + co + c * 8);
#pragma unroll
    for (int e = 0; e < 8; ++e) q[c * 8 + e] = bf2f(w[e]);
  }
  float s[3];
#pragma unroll
  for (int j = 0; j < 3; ++j) {
    float a = 0.f;
#pragma unroll
    for (int c = 0; c < 3; ++c) {
      u16x8 w = *(const u16x8*)(base + (size_t)j * 1536 + 384 + co + c * 8);
#pragma unroll
      for (int e = 0; e < 8; ++e) a += q[c * 8 + e] * bf2f(w[e]);
    }
    s[j] = a * 0.11785113019775793f;  // 1/sqrt(72)
  }
  float mx = fmaxf(s[0], fmaxf(s[1], s[2]));
  float e0 = __expf(s[0] - mx), e1 = __expf(s[1] - mx), e2 = __expf(s[2] - mx);
  float inv = 1.f / (e0 + e1 + e2);
  float p0 = e0 * inv, p1 = e1 * inv, p2 = e2 * inv;

  float o[24];
#pragma unroll
  for (int d = 0; d < 24; ++d) o[d] = 0.f;
  float pj[3] = {p0, p1, p2};
#pragma unroll
  for (int j = 0; j < 3; ++j) {
#pragma unroll
    for (int c = 0; c < 3; ++c) {
      u16x8 w = *(const u16x8*)(base + (size_t)j * 1536 + 768 + co + c * 8);
#pragma unroll
      for (int e = 0; e < 8; ++e) o[c * 8 + e] += pj[j] * bf2f(w[e]);
    }
  }
  unsigned short* op = Hout + (size_t)t * 1152 + (size_t)i * 384 + co;
#pragma unroll
  for (int c = 0; c < 3; ++c) {
    u16x8 w = *(const u16x8*)(base + (size_t)i * 1536 + 1152 + co + c * 8);
    u16x8 r;
#pragma unroll
    for (int e = 0; e < 8; ++e) {
      float gv = bf2f(w[e]);
      float sg = 1.f / (1.f + __expf(-gv));
      r[e] = f2bf(o[c * 8 + e] * sg);
    }
    *(u16x8*)(op + c * 8) = r;
  }
}

extern "C" void kernel_launch(void* const* d_in, const int* in_sizes, int n_in,
                              void* d_out, int out_size, void* d_ws, size_t ws_size,
                              hipStream_t stream) {
  const float* x    = (const float*)d_in[0];
  const float* ln_g = (const float*)d_in[1];
  const float* ln_b = (const float*)d_in[2];
  const float* Wq   = (const float*)d_in[3];
  const float* bq   = (const float*)d_in[4];
  const float* Wk   = (const float*)d_in[5];
  const float* bk   = (const float*)d_in[6];
  const float* Wv   = (const float*)d_in[7];
  const float* bv   = (const float*)d_in[8];
  const float* Wg   = (const float*)d_in[9];
  const float* bg   = (const float*)d_in[10];
  const float* Wo   = (const float*)d_in[11];
  const float* bo   = (const float*)d_in[12];
  const float* g    = (const float*)d_in[13];
  float* out = (float*)d_out;

  char* ws = (char*)d_ws;
  size_t off = 0;
  unsigned short* xn    = (unsigned short*)(ws + off); off += (size_t)T_ * D_ * 2;
  unsigned short* Wqkvg = (unsigned short*)(ws + off); off += (size_t)1536 * 384 * 2;
  unsigned short* Wob   = (unsigned short*)(ws + off); off += (size_t)1152 * 1152 * 2;
  unsigned short* QKVG  = (unsigned short*)(ws + off); off += (size_t)T_ * 3 * 1536 * 2;
  unsigned short* Hf    = (unsigned short*)(ws + off); off += (size_t)T_ * D_ * 2;

  ln_kernel<<<T_, 256, 0, stream>>>(x, ln_g, ln_b, xn);
  cvt_cat_wqkvg<<<(4 * 147456 + 255) / 256, 256, 0, stream>>>(Wq, Wk, Wv, Wg, Wqkvg);
  cvt_bf16<<<(1152 * 1152 + 255) / 256, 256, 0, stream>>>(Wo, Wob, 1152 * 1152);

  dim3 g1(1536 / 128, (T_ * 3) / 128);   // (12, 384) nwg=4608 = 6.0 rounds @3/CU
  gemm1_hi<<<g1, 512, 0, stream>>>(xn, Wqkvg, QKVG, bq, bk, bv, bg);

  attn_kernel<<<(T_ * H_ * 3) / 256, 256, 0, stream>>>(QKVG, Hf);

  dim3 g2(1152 / 96, T_ / 128);          // (12, 128) nwg=1536 = 2.0 rounds @3/CU
  gemm2_96<<<g2, 256, 0, stream>>>(Hf, Wob, out, bo, x, g);
}